// Round 1
// baseline (187.159 us; speedup 1.0000x reference)
//
#include <hip/hip_runtime.h>
#include <math.h>

#define B_  2
#define D_  1536
#define L_  2048
#define N_  16
#define NH  8                 // states per WAVE (wave w owns states [8w, 8w+8))
#define LC  256               // chunk length along L (64 lanes x 4 elems)
#define NCHUNK (L_ / LC)      // 8
#define NCH (B_ * D_)         // 3072 channels
#define LOG2E 1.4426950408889634f
#define LN2   0.6931471805599453f

typedef float f4 __attribute__((ext_vector_type(4)));
typedef float f8 __attribute__((ext_vector_type(8)));

__device__ __forceinline__ float exp2f_(float v) { return __builtin_amdgcn_exp2f(v); }
__device__ __forceinline__ float log2f_(float v) { return __builtin_amdgcn_logf(v); }
__device__ __forceinline__ float rcpf_(float v)  { return __builtin_amdgcn_rcpf(v); }

__device__ __forceinline__ float softplus_f(float v) {
    float t = exp2f_(v * LOG2E);                   // e^v
    float r = LN2 * log2f_(1.0f + t);              // ln(1+e^v)
    return (v > 20.0f) ? v : r;
}
__device__ __forceinline__ f8 splat8(float v) { f8 r = {v,v,v,v,v,v,v,v}; return r; }
__device__ __forceinline__ f8 exp2v8(f8 a) {
    f8 r;
    r[0]=exp2f_(a[0]); r[1]=exp2f_(a[1]); r[2]=exp2f_(a[2]); r[3]=exp2f_(a[3]);
    r[4]=exp2f_(a[4]); r[5]=exp2f_(a[5]); r[6]=exp2f_(a[6]); r[7]=exp2f_(a[7]);
    return r;
}
__device__ __forceinline__ float dot8(f8 a, f8 b) {
    float p0 = fmaf(a[0], b[0], a[1]*b[1]);
    float p1 = fmaf(a[2], b[2], a[3]*b[3]);
    float p2 = fmaf(a[4], b[4], a[5]*b[5]);
    float p3 = fmaf(a[6], b[6], a[7]*b[7]);
    return (p0 + p1) + (p2 + p3);
}

// DPP move with explicit identity for invalid/masked lanes (bound_ctrl=false
// and masked rows both produce `old`).
#define DPP_ROW_SHR(N) (0x110 + (N))
#define DPP_ROW_BCAST15 0x142
#define DPP_ROW_BCAST31 0x143
#define DPP_WAVE_SHR1   0x138
template<int CTRL, int RMASK>
__device__ __forceinline__ float updpp(float old, float v) {
    return __int_as_float(__builtin_amdgcn_update_dpp(
        __float_as_int(old), __float_as_int(v), CTRL, RMASK, 0xF, false));
}

// 2 waves per block = 1 channel. Wave w owns 8 of the 16 states; all 64 lanes
// of a wave are L-segments (lane owns 4 contiguous elems of a 256-chunk).
// vs the previous 1-wave/channel version: 2x total waves (24/CU -> all 3072
// blocks exactly co-resident at 6 waves/SIMD), serial chunk count 16 -> 8,
// wave64 DPP scan (row_shr 1/2/4/8, bcast15 row_mask 0xA folds row0->1 and
// row2->3, bcast31 row_mask 0xC folds lanes0-31 total into rows 2,3 — masked
// rows keep the neutral element, same identity trick as before).
// Each wave carries its own 8-state chunk carry; the only cross-wave coupling
// is the per-chunk y-sum via a double-buffered LDS exchange (1 barrier/chunk).
// delta/x for the NEXT chunk are software-prefetched (head of the dep chain).
__global__ __launch_bounds__(128, 6)
void ssm_scan_kernel(const float* __restrict__ x,
                     const float* __restrict__ delta,
                     const float* __restrict__ A,
                     const float* __restrict__ Bm,
                     const float* __restrict__ Cm,
                     const float* __restrict__ Dv,
                     const float* __restrict__ z,
                     const float* __restrict__ dbias,
                     float* __restrict__ out)
{
    const int tid  = threadIdx.x;      // 0..127
    const int lane = tid & 63;         // L-segment within chunk
    const int w    = tid >> 6;         // state-half owner
    const int ch   = blockIdx.x;       // one channel per block
    const int b    = ch / D_;
    const int d    = ch - b * D_;

    __shared__ f4 ybuf[2][64];         // wave1 -> wave0 y handoff, dbuf by chunk parity

    const float bias = dbias[d];
    const float Dd   = Dv[d];

    const float* Ab = A + d * N_ + NH * w;
    f8 A2v;
    A2v[0]=Ab[0]*LOG2E; A2v[1]=Ab[1]*LOG2E; A2v[2]=Ab[2]*LOG2E; A2v[3]=Ab[3]*LOG2E;
    A2v[4]=Ab[4]*LOG2E; A2v[5]=Ab[5]*LOG2E; A2v[6]=Ab[6]*LOG2E; A2v[7]=Ab[7]*LOG2E;

    const float* Bp = Bm + (size_t)b * (N_ * L_) + (size_t)(NH * w) * L_;
    const float* Cp = Cm + (size_t)b * (N_ * L_) + (size_t)(NH * w) * L_;
    const size_t chbase = (size_t)ch * L_;

    f8 carry = splat8(0.0f);

    // prefetched head-of-chain operands for chunk 0
    f4 dv = *(const f4*)(delta + chbase + lane * 4);
    f4 xv = *(const f4*)(x     + chbase + lane * 4);

    for (int c = 0; c < NCHUNK; ++c) {
        const int off  = c * LC + lane * 4;
        const int offn = ((c + 1) & (NCHUNK - 1)) * LC + lane * 4; // clamped wrap: last iter reloads chunk0 (harmless, L2-hot)

        // ---- loads for this chunk (dv/xv already in flight from prev iter) ----
        f4 zv = {0.0f, 0.0f, 0.0f, 0.0f};
        if (w == 0) zv = *(const f4*)(z + chbase + off);   // only the epilogue wave needs z
#define LD_BC(i) f4 Bv##i = *(const f4*)(Bp + i * L_ + off); \
                 f4 Cv##i = *(const f4*)(Cp + i * L_ + off);
        LD_BC(0) LD_BC(1) LD_BC(2) LD_BC(3) LD_BC(4) LD_BC(5) LD_BC(6) LD_BC(7)

        // ---- software prefetch: next chunk's critical-path loads ----
        f4 dvn = *(const f4*)(delta + chbase + offn);
        f4 xvn = *(const f4*)(x     + chbase + offn);

        // ---- dt / u / dtsum ----
        float dt0 = softplus_f(dv.x + bias);
        float dt1 = softplus_f(dv.y + bias);
        float dt2 = softplus_f(dv.z + bias);
        float dt3 = softplus_f(dv.w + bias);
        float u0 = dt0 * xv.x, u1 = dt1 * xv.y, u2 = dt2 * xv.z, u3 = dt3 * xv.w;
        float dtsum = (dt0 + dt1) + (dt2 + dt3);

        // ---- per-element deltaA vectors (kept for pass 2) ----
        f8 e0 = exp2v8(splat8(dt0) * A2v);
        f8 e1 = exp2v8(splat8(dt1) * A2v);
        f8 e2 = exp2v8(splat8(dt2) * A2v);
        f8 e3 = exp2v8(splat8(dt3) * A2v);
        f8 P  = exp2v8(splat8(dtsum) * A2v);

        // ---- transpose B/C fragments to per-j state-vectors ----
        f8 tB0 = {Bv0.x,Bv1.x,Bv2.x,Bv3.x,Bv4.x,Bv5.x,Bv6.x,Bv7.x};
        f8 tB1 = {Bv0.y,Bv1.y,Bv2.y,Bv3.y,Bv4.y,Bv5.y,Bv6.y,Bv7.y};
        f8 tB2 = {Bv0.z,Bv1.z,Bv2.z,Bv3.z,Bv4.z,Bv5.z,Bv6.z,Bv7.z};
        f8 tB3 = {Bv0.w,Bv1.w,Bv2.w,Bv3.w,Bv4.w,Bv5.w,Bv6.w,Bv7.w};
        f8 uB0 = splat8(u0) * tB0;
        f8 uB1 = splat8(u1) * tB1;
        f8 uB2 = splat8(u2) * tB2;
        f8 uB3 = splat8(u3) * tB3;
        f8 SC0 = {Cv0.x,Cv1.x,Cv2.x,Cv3.x,Cv4.x,Cv5.x,Cv6.x,Cv7.x};
        f8 SC1 = {Cv0.y,Cv1.y,Cv2.y,Cv3.y,Cv4.y,Cv5.y,Cv6.y,Cv7.y};
        f8 SC2 = {Cv0.z,Cv1.z,Cv2.z,Cv3.z,Cv4.z,Cv5.z,Cv6.z,Cv7.z};
        f8 SC3 = {Cv0.w,Cv1.w,Cv2.w,Cv3.w,Cv4.w,Cv5.w,Cv6.w,Cv7.w};

        // ---- pass 1: local 4-elem scan (start h=0) ----
        f8 S = uB0;
        S = e1 * S + uB1;
        S = e2 * S + uB2;
        S = e3 * S + uB3;

        // ---- width-64 inclusive scan of (P,S), all DPP/VALU ----
#define SCAN_STEP(CTRL, RMASK) \
        { \
            _Pragma("unroll") \
            for (int i = 0; i < NH; ++i) { \
                float Pp = updpp<CTRL, RMASK>(1.0f, P[i]); \
                float Sp = updpp<CTRL, RMASK>(0.0f, S[i]); \
                S[i] = fmaf(Sp, P[i], S[i]);   /* uses pre-update P */ \
                P[i] = P[i] * Pp; \
            } \
        }
        SCAN_STEP(DPP_ROW_SHR(1), 0xF)
        SCAN_STEP(DPP_ROW_SHR(2), 0xF)
        SCAN_STEP(DPP_ROW_SHR(4), 0xF)
        SCAN_STEP(DPP_ROW_SHR(8), 0xF)
        SCAN_STEP(DPP_ROW_BCAST15, 0xA)  // rows 1,3 get rows 0,2 totals; rows 0,2 keep neutral
        SCAN_STEP(DPP_ROW_BCAST31, 0xC)  // rows 2,3 get lanes0-31 total; rows 0,1 keep neutral

        // ---- fold chunk carry; h entering this lane's segment ----
        f8 h;
#pragma unroll
        for (int i = 0; i < NH; ++i) {
            float hinc = fmaf(carry[i], P[i], S[i]);            // true inclusive state
            float hup  = updpp<DPP_WAVE_SHR1, 0xF>(0.0f, hinc); // lane n <- n-1 (valid across lane 32 now)
            h[i] = (lane == 0) ? carry[i] : hup;                // only lane 0 starts from carry
            carry[i] = __shfl(hinc, 63, 64);                    // broadcast wave total
        }

        // ---- pass 2: recurrence (reusing e_j, uB_j); y_j = <h, C_j> ----
        h = e0 * h + uB0;  float y0 = dot8(h, SC0);
        h = e1 * h + uB1;  float y1 = dot8(h, SC1);
        h = e2 * h + uB2;  float y2 = dot8(h, SC2);
        h = e3 * h + uB3;  float y3 = dot8(h, SC3);

        // ---- combine the two state-halves across waves; epilogue; store ----
        if (w == 1) {
            f4 yv = { y0, y1, y2, y3 };
            ybuf[c & 1][lane] = yv;
        }
        __syncthreads();   // dbuf by parity: wave1's next write targets the other buffer,
                           // and its return to THIS buffer sits behind the next barrier
        if (w == 0) {
            f4 yo = ybuf[c & 1][lane];
            float s0 = rcpf_(1.0f + exp2f_(-zv.x * LOG2E));
            float s1 = rcpf_(1.0f + exp2f_(-zv.y * LOG2E));
            float s2 = rcpf_(1.0f + exp2f_(-zv.z * LOG2E));
            float s3 = rcpf_(1.0f + exp2f_(-zv.w * LOG2E));
            f4 ov = { (y0 + yo.x + xv.x * Dd) * (zv.x * s0),
                      (y1 + yo.y + xv.y * Dd) * (zv.y * s1),
                      (y2 + yo.z + xv.z * Dd) * (zv.z * s2),
                      (y3 + yo.w + xv.w * Dd) * (zv.w * s3) };
            *(f4*)(out + chbase + off) = ov;
        }
        dv = dvn; xv = xvn;
    }
}

extern "C" void kernel_launch(void* const* d_in, const int* in_sizes, int n_in,
                              void* d_out, int out_size, void* d_ws, size_t ws_size,
                              hipStream_t stream) {
    const float* x     = (const float*)d_in[0];
    const float* delta = (const float*)d_in[1];
    const float* A     = (const float*)d_in[2];
    const float* Bm    = (const float*)d_in[3];
    const float* Cm    = (const float*)d_in[4];
    const float* Dv    = (const float*)d_in[5];
    const float* z     = (const float*)d_in[6];
    const float* dbias = (const float*)d_in[7];
    float* out = (float*)d_out;

    dim3 grid(NCH);    // 3072 blocks = 2 waves = 1 channel each
    dim3 block(128);
    ssm_scan_kernel<<<grid, block, 0, stream>>>(x, delta, A, Bm, Cm, Dv, z, dbias, out);
}

// Round 2
// 166.633 us; speedup vs baseline: 1.1232x; 1.1232x over previous
//
#include <hip/hip_runtime.h>
#include <math.h>

#define B_  2
#define D_  1536
#define L_  2048
#define N_  16
#define NH  8                 // states per half-wave
#define LC  128               // chunk length along L (32 segs x 4 elems)
#define NCHUNK (L_ / LC)      // 16
#define NCH (B_ * D_)         // 3072 channels
#define LOG2E 1.4426950408889634f
#define LN2   0.6931471805599453f

typedef float f4 __attribute__((ext_vector_type(4)));
typedef float f8 __attribute__((ext_vector_type(8)));

__device__ __forceinline__ float exp2f_(float v) { return __builtin_amdgcn_exp2f(v); }
__device__ __forceinline__ float log2f_(float v) { return __builtin_amdgcn_logf(v); }
__device__ __forceinline__ float rcpf_(float v)  { return __builtin_amdgcn_rcpf(v); }

__device__ __forceinline__ float softplus_f(float v) {
    float t = exp2f_(v * LOG2E);                   // e^v
    float r = LN2 * log2f_(1.0f + t);              // ln(1+e^v)
    return (v > 20.0f) ? v : r;
}
__device__ __forceinline__ f8 splat8(float v) { f8 r = {v,v,v,v,v,v,v,v}; return r; }
__device__ __forceinline__ f8 exp2v8(f8 a) {
    f8 r;
    r[0]=exp2f_(a[0]); r[1]=exp2f_(a[1]); r[2]=exp2f_(a[2]); r[3]=exp2f_(a[3]);
    r[4]=exp2f_(a[4]); r[5]=exp2f_(a[5]); r[6]=exp2f_(a[6]); r[7]=exp2f_(a[7]);
    return r;
}
__device__ __forceinline__ float dot8(f8 a, f8 b) {
    float p0 = fmaf(a[0], b[0], a[1]*b[1]);
    float p1 = fmaf(a[2], b[2], a[3]*b[3]);
    float p2 = fmaf(a[4], b[4], a[5]*b[5]);
    float p3 = fmaf(a[6], b[6], a[7]*b[7]);
    return (p0 + p1) + (p2 + p3);
}

// DPP move with explicit identity for invalid/masked lanes (bound_ctrl=false
// and masked rows both produce `old`).
#define DPP_ROW_SHR(N) (0x110 + (N))
#define DPP_ROW_BCAST15 0x142
#define DPP_WAVE_SHR1   0x138
template<int CTRL, int RMASK>
__device__ __forceinline__ float updpp(float old, float v) {
    return __int_as_float(__builtin_amdgcn_update_dpp(
        __float_as_int(old), __float_as_int(v), CTRL, RMASK, 0xF, false));
}

// One wave (= one 64-thread block) per channel (round-0 structure restored:
// the 2-wave split doubled HBM traffic + added a barrier and regressed).
// lane=(g,s): g=lane>>5 owns 8 of 16 states, s=lane&31 owns a 4-elem segment.
//
// NEW vs round-0: register double-buffered prefetch of the EARLY-consumed
// operands (delta, x, B rows) one chunk ahead.  Theory: all blocks are
// identical and phase-locked, so every resident wave hit its chunk-head
// B-load L2 wait simultaneously — a correlated stall that more waves (round 1)
// could not hide.  Prefetch hides it within the wave: chunk c's B/delta/x are
// issued during chunk c-1's compute (~2000 cy of cover).  C and z are issued
// at the body top and consumed ~700-1000 cy later (pass 2 / epilogue) — their
// latency is already covered, so they are NOT double-buffered (saves 36 VGPRs).
// Manual unroll-by-2 with static buffer names (runtime-indexed buffers would
// go to scratch).  P is now the product e0*e1*e2*e3 (3 f8 muls) instead of a
// fresh 8-exp evaluation of exp2(dtsum*A).
__global__ __launch_bounds__(64, 3)
void ssm_scan_kernel(const float* __restrict__ x,
                     const float* __restrict__ delta,
                     const float* __restrict__ A,
                     const float* __restrict__ Bm,
                     const float* __restrict__ Cm,
                     const float* __restrict__ Dv,
                     const float* __restrict__ z,
                     const float* __restrict__ dbias,
                     float* __restrict__ out)
{
    const int lane = threadIdx.x;      // 0..63
    const int s    = lane & 31;
    const int g    = lane >> 5;
    const int ch   = blockIdx.x;       // one channel per wave
    const int b    = ch / D_;
    const int d    = ch - b * D_;

    const float bias = dbias[d];
    const float Dd   = Dv[d];

    const float* Ab = A + d * N_ + NH * g;
    f8 A2v;
    A2v[0]=Ab[0]*LOG2E; A2v[1]=Ab[1]*LOG2E; A2v[2]=Ab[2]*LOG2E; A2v[3]=Ab[3]*LOG2E;
    A2v[4]=Ab[4]*LOG2E; A2v[5]=Ab[5]*LOG2E; A2v[6]=Ab[6]*LOG2E; A2v[7]=Ab[7]*LOG2E;

    const float* Bp = Bm + (size_t)b * (N_ * L_) + (size_t)(NH * g) * L_;
    const float* Cp = Cm + (size_t)b * (N_ * L_) + (size_t)(NH * g) * L_;
    const size_t chbase = (size_t)ch * L_;

    f8 carry = splat8(0.0f);

    // ---- prefetch chunk 0's early-consumed operands into buffer P0 ----
    f4 P0_dv = *(const f4*)(delta + chbase + s * 4);
    f4 P0_xv = *(const f4*)(x     + chbase + s * 4);
    f4 P0_B0 = *(const f4*)(Bp + 0 * L_ + s * 4);
    f4 P0_B1 = *(const f4*)(Bp + 1 * L_ + s * 4);
    f4 P0_B2 = *(const f4*)(Bp + 2 * L_ + s * 4);
    f4 P0_B3 = *(const f4*)(Bp + 3 * L_ + s * 4);
    f4 P0_B4 = *(const f4*)(Bp + 4 * L_ + s * 4);
    f4 P0_B5 = *(const f4*)(Bp + 5 * L_ + s * 4);
    f4 P0_B6 = *(const f4*)(Bp + 6 * L_ + s * 4);
    f4 P0_B7 = *(const f4*)(Bp + 7 * L_ + s * 4);
    f4 P1_dv, P1_xv, P1_B0, P1_B1, P1_B2, P1_B3, P1_B4, P1_B5, P1_B6, P1_B7;

#define BODY(c, CUR, NXT) { \
    const int off  = (c) * LC + s * 4; \
    const int offn = (((c) + 1) & (NCHUNK - 1)) * LC + s * 4; /* wrap: last iter reloads chunk0, harmless */ \
    /* ---- current-chunk late-use loads (covered by pass1+scan latency) ---- */ \
    f4 zv  = *(const f4*)(z + chbase + off); \
    f4 Cv0 = *(const f4*)(Cp + 0 * L_ + off); \
    f4 Cv1 = *(const f4*)(Cp + 1 * L_ + off); \
    f4 Cv2 = *(const f4*)(Cp + 2 * L_ + off); \
    f4 Cv3 = *(const f4*)(Cp + 3 * L_ + off); \
    f4 Cv4 = *(const f4*)(Cp + 4 * L_ + off); \
    f4 Cv5 = *(const f4*)(Cp + 5 * L_ + off); \
    f4 Cv6 = *(const f4*)(Cp + 6 * L_ + off); \
    f4 Cv7 = *(const f4*)(Cp + 7 * L_ + off); \
    /* ---- next-chunk early-use prefetch (consumed next iteration) ---- */ \
    NXT##_dv = *(const f4*)(delta + chbase + offn); \
    NXT##_xv = *(const f4*)(x     + chbase + offn); \
    NXT##_B0 = *(const f4*)(Bp + 0 * L_ + offn); \
    NXT##_B1 = *(const f4*)(Bp + 1 * L_ + offn); \
    NXT##_B2 = *(const f4*)(Bp + 2 * L_ + offn); \
    NXT##_B3 = *(const f4*)(Bp + 3 * L_ + offn); \
    NXT##_B4 = *(const f4*)(Bp + 4 * L_ + offn); \
    NXT##_B5 = *(const f4*)(Bp + 5 * L_ + offn); \
    NXT##_B6 = *(const f4*)(Bp + 6 * L_ + offn); \
    NXT##_B7 = *(const f4*)(Bp + 7 * L_ + offn); \
    /* ---- dt / u ---- */ \
    float dt0 = softplus_f(CUR##_dv.x + bias); \
    float dt1 = softplus_f(CUR##_dv.y + bias); \
    float dt2 = softplus_f(CUR##_dv.z + bias); \
    float dt3 = softplus_f(CUR##_dv.w + bias); \
    float u0 = dt0 * CUR##_xv.x, u1 = dt1 * CUR##_xv.y; \
    float u2 = dt2 * CUR##_xv.z, u3 = dt3 * CUR##_xv.w; \
    /* ---- per-element deltaA vectors (kept for pass 2) ---- */ \
    f8 e0 = exp2v8(splat8(dt0) * A2v); \
    f8 e1 = exp2v8(splat8(dt1) * A2v); \
    f8 e2 = exp2v8(splat8(dt2) * A2v); \
    f8 e3 = exp2v8(splat8(dt3) * A2v); \
    f8 P  = (e0 * e1) * (e2 * e3);     /* segment-total decay, no extra exps */ \
    /* ---- transpose B/C fragments to per-j state-vectors ---- */ \
    f8 tB0 = {CUR##_B0.x,CUR##_B1.x,CUR##_B2.x,CUR##_B3.x,CUR##_B4.x,CUR##_B5.x,CUR##_B6.x,CUR##_B7.x}; \
    f8 tB1 = {CUR##_B0.y,CUR##_B1.y,CUR##_B2.y,CUR##_B3.y,CUR##_B4.y,CUR##_B5.y,CUR##_B6.y,CUR##_B7.y}; \
    f8 tB2 = {CUR##_B0.z,CUR##_B1.z,CUR##_B2.z,CUR##_B3.z,CUR##_B4.z,CUR##_B5.z,CUR##_B6.z,CUR##_B7.z}; \
    f8 tB3 = {CUR##_B0.w,CUR##_B1.w,CUR##_B2.w,CUR##_B3.w,CUR##_B4.w,CUR##_B5.w,CUR##_B6.w,CUR##_B7.w}; \
    f8 uB0 = splat8(u0) * tB0; \
    f8 uB1 = splat8(u1) * tB1; \
    f8 uB2 = splat8(u2) * tB2; \
    f8 uB3 = splat8(u3) * tB3; \
    f8 SC0 = {Cv0.x,Cv1.x,Cv2.x,Cv3.x,Cv4.x,Cv5.x,Cv6.x,Cv7.x}; \
    f8 SC1 = {Cv0.y,Cv1.y,Cv2.y,Cv3.y,Cv4.y,Cv5.y,Cv6.y,Cv7.y}; \
    f8 SC2 = {Cv0.z,Cv1.z,Cv2.z,Cv3.z,Cv4.z,Cv5.z,Cv6.z,Cv7.z}; \
    f8 SC3 = {Cv0.w,Cv1.w,Cv2.w,Cv3.w,Cv4.w,Cv5.w,Cv6.w,Cv7.w}; \
    /* ---- pass 1: local 4-elem scan (start h=0) ---- */ \
    f8 S = uB0; \
    S = e1 * S + uB1; \
    S = e2 * S + uB2; \
    S = e3 * S + uB3; \
    /* ---- width-32 inclusive scan of (P,S), all DPP/VALU ---- */ \
    SCAN_STEP(DPP_ROW_SHR(1), 0xF) \
    SCAN_STEP(DPP_ROW_SHR(2), 0xF) \
    SCAN_STEP(DPP_ROW_SHR(4), 0xF) \
    SCAN_STEP(DPP_ROW_SHR(8), 0xF) \
    SCAN_STEP(DPP_ROW_BCAST15, 0xA)  /* rows 1,3 only; rows 0,2 keep neutral */ \
    /* ---- fold chunk carry; h entering this lane's segment ---- */ \
    f8 h; \
    _Pragma("unroll") \
    for (int i = 0; i < NH; ++i) { \
        float hinc = fmaf(carry[i], P[i], S[i]);            /* true inclusive state */ \
        float hup  = updpp<DPP_WAVE_SHR1, 0xF>(0.0f, hinc); /* lane n <- n-1 */ \
        h[i] = (s == 0) ? carry[i] : hup;                   /* fixes lanes 0 and 32 */ \
        carry[i] = __shfl(hinc, 31, 32);                    /* broadcast within half */ \
    } \
    /* ---- pass 2: recurrence (reusing e_j, uB_j); y_j = <h, C_j> ---- */ \
    h = e0 * h + uB0;  float y0 = dot8(h, SC0); \
    h = e1 * h + uB1;  float y1 = dot8(h, SC1); \
    h = e2 * h + uB2;  float y2 = dot8(h, SC2); \
    h = e3 * h + uB3;  float y3 = dot8(h, SC3); \
    /* ---- combine the two state-halves; epilogue; half-wave store ---- */ \
    y0 += __shfl_xor(y0, 32, 64); \
    y1 += __shfl_xor(y1, 32, 64); \
    y2 += __shfl_xor(y2, 32, 64); \
    y3 += __shfl_xor(y3, 32, 64); \
    if (g == 0) { \
        float s0 = rcpf_(1.0f + exp2f_(-zv.x * LOG2E)); \
        float s1 = rcpf_(1.0f + exp2f_(-zv.y * LOG2E)); \
        float s2 = rcpf_(1.0f + exp2f_(-zv.z * LOG2E)); \
        float s3 = rcpf_(1.0f + exp2f_(-zv.w * LOG2E)); \
        f4 ov = { (y0 + CUR##_xv.x * Dd) * (zv.x * s0), \
                  (y1 + CUR##_xv.y * Dd) * (zv.y * s1), \
                  (y2 + CUR##_xv.z * Dd) * (zv.z * s2), \
                  (y3 + CUR##_xv.w * Dd) * (zv.w * s3) }; \
        *(f4*)(out + chbase + off) = ov; \
    } \
}

#define SCAN_STEP(CTRL, RMASK) \
    { \
        _Pragma("unroll") \
        for (int i = 0; i < NH; ++i) { \
            float Pp = updpp<CTRL, RMASK>(1.0f, P[i]); \
            float Sp = updpp<CTRL, RMASK>(0.0f, S[i]); \
            S[i] = fmaf(Sp, P[i], S[i]);   /* uses pre-update P */ \
            P[i] = P[i] * Pp; \
        } \
    }

    for (int cc = 0; cc < NCHUNK; cc += 2) {
        BODY(cc,     P0, P1)
        BODY(cc + 1, P1, P0)
    }
}

extern "C" void kernel_launch(void* const* d_in, const int* in_sizes, int n_in,
                              void* d_out, int out_size, void* d_ws, size_t ws_size,
                              hipStream_t stream) {
    const float* x     = (const float*)d_in[0];
    const float* delta = (const float*)d_in[1];
    const float* A     = (const float*)d_in[2];
    const float* Bm    = (const float*)d_in[3];
    const float* Cm    = (const float*)d_in[4];
    const float* Dv    = (const float*)d_in[5];
    const float* z     = (const float*)d_in[6];
    const float* dbias = (const float*)d_in[7];
    float* out = (float*)d_out;

    dim3 grid(NCH);    // 3072 blocks = 1 wave = 1 channel each
    dim3 block(64);
    ssm_scan_kernel<<<grid, block, 0, stream>>>(x, delta, A, Bm, Cm, Dv, z, dbias, out);
}